// Round 1
// baseline (3143.094 us; speedup 1.0000x reference)
//
#include <hip/hip_runtime.h>

// 2-layer ReLU RNN, H=128, B=128, T=2048.
// One workgroup per batch element (128 WGs). 256 threads:
//   threads 0..127   : layer-0, thread i owns output unit i, holds W rows in VGPRs
//   threads 128..255 : layer-1, pipelined one step behind layer-0
// h-states in double-buffered LDS (broadcast reads). x streamed in 32KB chunks
// via register-staged prefetch (issue at chunk start, LDS-write at chunk end).

constexpr int H      = 128;
constexpr int T      = 2048;
constexpr int CHUNK  = 64;           // timesteps per x chunk (64*128*4 = 32 KB)
constexpr int NCHUNK = T / CHUNK;    // 32

__global__ __launch_bounds__(256, 1)
void rnn2_kernel(const float* __restrict__ x,
                 const float* __restrict__ Wih,
                 const float* __restrict__ Whh,
                 const float* __restrict__ bih,
                 const float* __restrict__ bhh,
                 float* __restrict__ out)
{
    __shared__ float xbuf[2][CHUNK * H];   // 64 KB, double-buffered x chunks
    __shared__ float h0buf[2][H];          // layer-0 hidden state (double buffer)
    __shared__ float h1buf[2][H];          // layer-1 hidden state (double buffer)

    const int b     = blockIdx.x;
    const int tid   = threadIdx.x;
    const int layer = tid >> 7;            // 0 or 1 (uniform per wave)
    const int unit  = tid & (H - 1);

    // ---- weight rows into registers (256 VGPRs) ----
    float wih[H], whh[H];
    {
        const float* wi = Wih + (size_t)layer * H * H + (size_t)unit * H;
        const float* wh = Whh + (size_t)layer * H * H + (size_t)unit * H;
#pragma unroll
        for (int j = 0; j < H; j += 4) {
            float4 a = *reinterpret_cast<const float4*>(wi + j);
            wih[j] = a.x; wih[j + 1] = a.y; wih[j + 2] = a.z; wih[j + 3] = a.w;
            float4 c = *reinterpret_cast<const float4*>(wh + j);
            whh[j] = c.x; whh[j + 1] = c.y; whh[j + 2] = c.z; whh[j + 3] = c.w;
        }
    }
    const float bias = bih[layer * H + unit] + bhh[layer * H + unit];

    if (tid < H) {
        h0buf[0][tid] = 0.f; h0buf[1][tid] = 0.f;
        h1buf[0][tid] = 0.f; h1buf[1][tid] = 0.f;
    }

    const float* xsrc = x + (size_t)b * T * H;

    // ---- preload chunk 0 (coalesced: 256 threads x 8 float4) ----
    float4 stage[8];
    {
        const float4* src = reinterpret_cast<const float4*>(xsrc);
#pragma unroll
        for (int q = 0; q < 8; ++q) stage[q] = src[q * 256 + tid];
        float4* dst = reinterpret_cast<float4*>(xbuf[0]);
#pragma unroll
        for (int q = 0; q < 8; ++q) dst[q * 256 + tid] = stage[q];
    }
    __syncthreads();

    int cur = 0;
#pragma unroll 1
    for (int p = 0; p < T; ++p) {
        const int c  = p >> 6;             // chunk index
        const int ip = p & (CHUNK - 1);    // step within chunk
        const int cb = c & 1;

        // issue next chunk's global loads early (latency hides under ~64 phases)
        if (ip == 0 && (c + 1) < NCHUNK) {
            const float4* src =
                reinterpret_cast<const float4*>(xsrc + (size_t)(c + 1) * CHUNK * H);
#pragma unroll
            for (int q = 0; q < 8; ++q) stage[q] = src[q * 256 + tid];
        }

        // phase p: layer0 computes h0(p) from x(p), h0(p-1)
        //          layer1 computes h1(p-1) from h0(p-1), h1(p-2)
        const float* invec = layer ? h0buf[cur] : (xbuf[cb] + ip * H);
        const float* stvec = layer ? h1buf[cur] : h0buf[cur];

        float a0 = 0.f, a1 = 0.f, a2 = 0.f, a3 = 0.f;
        float a4 = 0.f, a5 = 0.f, a6 = 0.f, a7 = 0.f;
#pragma unroll
        for (int j = 0; j < H; j += 4) {
            float4 iv = *reinterpret_cast<const float4*>(invec + j);
            float4 sv = *reinterpret_cast<const float4*>(stvec + j);
            a0 = fmaf(wih[j    ], iv.x, a0);
            a1 = fmaf(wih[j + 1], iv.y, a1);
            a2 = fmaf(wih[j + 2], iv.z, a2);
            a3 = fmaf(wih[j + 3], iv.w, a3);
            a4 = fmaf(whh[j    ], sv.x, a4);
            a5 = fmaf(whh[j + 1], sv.y, a5);
            a6 = fmaf(whh[j + 2], sv.z, a6);
            a7 = fmaf(whh[j + 3], sv.w, a7);
        }
        float hnew =
            fmaxf(((a0 + a1) + (a2 + a3)) + ((a4 + a5) + (a6 + a7)) + bias, 0.f);
        if (p == 0 && layer) hnew = 0.f;   // h1(-1) must stay 0

        float* outb = layer ? h1buf[cur ^ 1] : h0buf[cur ^ 1];
        outb[unit] = hnew;

        // write staged chunk into the other x buffer at chunk end
        if (ip == CHUNK - 1 && (c + 1) < NCHUNK) {
            float4* dst = reinterpret_cast<float4*>(xbuf[cb ^ 1]);
#pragma unroll
            for (int q = 0; q < 8; ++q) dst[q * 256 + tid] = stage[q];
        }

        __syncthreads();
        cur ^= 1;
    }

    // epilogue phase p=T: layer1 computes h1(T-1); only unit 3 is needed.
    if (tid == H + 3) {
        const float* h0c = h0buf[cur];   // h0(T-1)
        const float* h1c = h1buf[cur];   // h1(T-2)
        float a0 = 0.f, a1 = 0.f, a2 = 0.f, a3 = 0.f;
        float a4 = 0.f, a5 = 0.f, a6 = 0.f, a7 = 0.f;
#pragma unroll
        for (int j = 0; j < H; j += 4) {
            a0 = fmaf(wih[j    ], h0c[j    ], a0);
            a1 = fmaf(wih[j + 1], h0c[j + 1], a1);
            a2 = fmaf(wih[j + 2], h0c[j + 2], a2);
            a3 = fmaf(wih[j + 3], h0c[j + 3], a3);
            a4 = fmaf(whh[j    ], h1c[j    ], a4);
            a5 = fmaf(whh[j + 1], h1c[j + 1], a5);
            a6 = fmaf(whh[j + 2], h1c[j + 2], a6);
            a7 = fmaf(whh[j + 3], h1c[j + 3], a7);
        }
        out[b] =
            fmaxf(((a0 + a1) + (a2 + a3)) + ((a4 + a5) + (a6 + a7)) + bias, 0.f);
    }
}

extern "C" void kernel_launch(void* const* d_in, const int* in_sizes, int n_in,
                              void* d_out, int out_size, void* d_ws, size_t ws_size,
                              hipStream_t stream)
{
    const float* x   = (const float*)d_in[0];
    const float* Wih = (const float*)d_in[1];
    const float* Whh = (const float*)d_in[2];
    const float* bih = (const float*)d_in[3];
    const float* bhh = (const float*)d_in[4];
    float* out = (float*)d_out;

    rnn2_kernel<<<dim3(128), dim3(256), 0, stream>>>(x, Wih, Whh, bih, bhh, out);
}